// Round 1
// baseline (333.788 us; speedup 1.0000x reference)
//
#include <hip/hip_runtime.h>

// LIF neuron scan: u = u*DECAY + x_t; s = (u - V_TH > 0); u *= (1 - s).
// T=4 sequential steps, fully parallel over the 12.8M spatial slots.
// Memory-bound: ~411 MB total traffic -> ~65 us roofline at 6.3 TB/s.

#define V_TH  1.0f
#define DECAY 0.25f

// N per timestep = 32*128*56*56 = 12,845,056 floats = 3,211,264 float4s.
// float4 per lane = 16 B coalescing sweet spot.

__global__ __launch_bounds__(256) void lif_kernel(const float4* __restrict__ x,
                                                  float4* __restrict__ out,
                                                  int n4) {
    const int i = blockIdx.x * 256 + threadIdx.x;
    if (i >= n4) return;

    // Load all 4 time planes up front (independent loads -> max MLP).
    float4 x0 = x[(size_t)0 * n4 + i];
    float4 x1 = x[(size_t)1 * n4 + i];
    float4 x2 = x[(size_t)2 * n4 + i];
    float4 x3 = x[(size_t)3 * n4 + i];

    float4 u = make_float4(0.f, 0.f, 0.f, 0.f);
    float4 s0, s1, s2, s3;

    // Step macro: u = u*DECAY + xt (exact: DECAY is 2^-2); spike; hard reset.
#define LIF_STEP(xt, st)                                                      \
    do {                                                                      \
        u.x = u.x * DECAY + (xt).x;                                           \
        u.y = u.y * DECAY + (xt).y;                                           \
        u.z = u.z * DECAY + (xt).z;                                           \
        u.w = u.w * DECAY + (xt).w;                                           \
        (st).x = (u.x - V_TH > 0.f) ? 1.f : 0.f;                              \
        (st).y = (u.y - V_TH > 0.f) ? 1.f : 0.f;                              \
        (st).z = (u.z - V_TH > 0.f) ? 1.f : 0.f;                              \
        (st).w = (u.w - V_TH > 0.f) ? 1.f : 0.f;                              \
        u.x = ((st).x > 0.f) ? 0.f : u.x;                                     \
        u.y = ((st).y > 0.f) ? 0.f : u.y;                                     \
        u.z = ((st).z > 0.f) ? 0.f : u.z;                                     \
        u.w = ((st).w > 0.f) ? 0.f : u.w;                                     \
    } while (0)

    LIF_STEP(x0, s0);
    LIF_STEP(x1, s1);
    LIF_STEP(x2, s2);
    LIF_STEP(x3, s3);
#undef LIF_STEP

    out[(size_t)0 * n4 + i] = s0;
    out[(size_t)1 * n4 + i] = s1;
    out[(size_t)2 * n4 + i] = s2;
    out[(size_t)3 * n4 + i] = s3;
}

extern "C" void kernel_launch(void* const* d_in, const int* in_sizes, int n_in,
                              void* d_out, int out_size, void* d_ws, size_t ws_size,
                              hipStream_t stream) {
    const float4* x = (const float4*)d_in[0];
    float4* out = (float4*)d_out;

    // out_size = T*B*C*H*W; per-timestep plane = out_size/4; float4 count = /4 again.
    const int n4 = out_size / 4 / 4;  // 3,211,264
    const int block = 256;
    const int grid = (n4 + block - 1) / block;  // 12,544 blocks

    lif_kernel<<<grid, block, 0, stream>>>(x, out, n4);
}

// Round 3
// 325.092 us; speedup vs baseline: 1.0268x; 1.0268x over previous
//
#include <hip/hip_runtime.h>

// LIF neuron scan: u = u*DECAY + x_t; s = (u - V_TH > 0); u *= (1 - s).
// T=4 sequential steps, fully parallel over the 12.8M spatial slots.
// Memory-bound: 205.5 MB read + 205.5 MB write = 411 MB -> ~63 us floor
// at the measured 6.5 TB/s fill ceiling.
//
// R1: kernel absent from rocprof top-5 (all 126-us harness fills) => kernel
// <= 125 us; bench dur_us=334 includes harness restore/poison traffic.
// R2: __builtin_nontemporal_* rejects HIP_vector_type (class). Use clang
// ext_vector_type(4) instead — native vector, builtin-compatible, still 16 B.

#define V_TH  1.0f
#define DECAY 0.25f

typedef float v4f __attribute__((ext_vector_type(4)));

__global__ __launch_bounds__(256) void lif_kernel(const v4f* __restrict__ x,
                                                  v4f* __restrict__ out,
                                                  int n4) {
    int i = blockIdx.x * 256 + threadIdx.x;
    const int stride = gridDim.x * 256;

    for (; i < n4; i += stride) {
        // Load all 4 time planes up front (independent loads -> max MLP).
        // Nontemporal: input is single-use streaming data.
        v4f x0 = __builtin_nontemporal_load(&x[(size_t)0 * n4 + i]);
        v4f x1 = __builtin_nontemporal_load(&x[(size_t)1 * n4 + i]);
        v4f x2 = __builtin_nontemporal_load(&x[(size_t)2 * n4 + i]);
        v4f x3 = __builtin_nontemporal_load(&x[(size_t)3 * n4 + i]);

        v4f u = (v4f)(0.f);
        v4f s0, s1, s2, s3;

        // Step: u = u*DECAY + xt (exact: DECAY is 2^-2); spike; hard reset.
        // Element-wise on ext vectors; select via per-element ternary.
#define LIF_STEP(xt, st)                                                      \
        do {                                                                  \
            u = u * DECAY + (xt);                                             \
            (st).x = (u.x > V_TH) ? 1.f : 0.f;                                \
            (st).y = (u.y > V_TH) ? 1.f : 0.f;                                \
            (st).z = (u.z > V_TH) ? 1.f : 0.f;                                \
            (st).w = (u.w > V_TH) ? 1.f : 0.f;                                \
            u.x = (u.x > V_TH) ? 0.f : u.x;                                   \
            u.y = (u.y > V_TH) ? 0.f : u.y;                                   \
            u.z = (u.z > V_TH) ? 0.f : u.z;                                   \
            u.w = (u.w > V_TH) ? 0.f : u.w;                                   \
        } while (0)

        LIF_STEP(x0, s0);
        LIF_STEP(x1, s1);
        LIF_STEP(x2, s2);
        LIF_STEP(x3, s3);
#undef LIF_STEP

        // Nontemporal: output is write-once, never re-read by us.
        __builtin_nontemporal_store(s0, &out[(size_t)0 * n4 + i]);
        __builtin_nontemporal_store(s1, &out[(size_t)1 * n4 + i]);
        __builtin_nontemporal_store(s2, &out[(size_t)2 * n4 + i]);
        __builtin_nontemporal_store(s3, &out[(size_t)3 * n4 + i]);
    }
}

extern "C" void kernel_launch(void* const* d_in, const int* in_sizes, int n_in,
                              void* d_out, int out_size, void* d_ws, size_t ws_size,
                              hipStream_t stream) {
    const v4f* x = (const v4f*)d_in[0];
    v4f* out = (v4f*)d_out;

    // out_size = T*B*C*H*W; per-timestep plane = out_size/4; float4 count = /4.
    const int n4 = out_size / 4 / 4;  // 3,211,264
    const int block = 256;
    const int grid = (n4 + block - 1) / block;  // 12,544 blocks (grid-stride safe)

    lif_kernel<<<grid, block, 0, stream>>>(x, out, n4);
}